// Round 5
// baseline (272.275 us; speedup 1.0000x reference)
//
#include <hip/hip_runtime.h>

#define N_NODES 100000
#define N_EDGES 600000
#define DIM 128

typedef __attribute__((ext_vector_type(8))) short bf16x8;
typedef __attribute__((ext_vector_type(4))) float f32x4;

typedef __attribute__((address_space(1))) const unsigned int g_u32;
typedef __attribute__((address_space(3))) unsigned int l_u32;
__device__ __forceinline__ void stage16(const void* g, void* l) {
  __builtin_amdgcn_global_load_lds((g_u32*)g, (l_u32*)l, 16, 0, 0);
}

__device__ __forceinline__ unsigned short f32_to_bf16_rn(float f) {
  unsigned int u = __builtin_bit_cast(unsigned int, f);
  unsigned int r = (u + 0x7FFFu + ((u >> 16) & 1u)) >> 16;
  return (unsigned short)r;
}
__device__ __forceinline__ float bf16_to_f32(unsigned short h) {
  return __builtin_bit_cast(float, (unsigned int)h << 16);
}

// pack one f32 into u32 = (hi_bf16 << 16) | lo_bf16, hi=rn(v), lo=rn(v-hi)
__device__ __forceinline__ unsigned int pack_hl(float v) {
  const unsigned int u = __builtin_bit_cast(unsigned int, v);
  const unsigned int r1 = u + 0x7FFFu + ((u >> 16) & 1u);
  const unsigned int hb = r1 & 0xFFFF0000u;  // bf(hi) bits
  const float fl = v - __builtin_bit_cast(float, hb);
  const unsigned int u2 = __builtin_bit_cast(unsigned int, fl);
  const unsigned int r2 = (u2 + 0x7FFFu + ((u2 >> 16) & 1u)) >> 16;
  return hb | (r2 & 0xFFFFu);
}

// ---------------- pack weights into MFMA fragment order ----------------
// g-tile sequence (4096 shorts each): [Wl_hi k0-31, Wl_lo k0-31, Wl_hi k32-63,
// Wl_lo k32-63, ... , Wr_hi k0-31, Wr_lo k0-31, ...]
// packed[((g*8+nt)*64+l)*8+j] = plane[(g>>1)&3 k-tile][(l>>4)*8+j][nt*16+(l&15)]
__global__ __launch_bounds__(256) void pack_w_k(const float* __restrict__ Wl,
                                                const float* __restrict__ Wr,
                                                unsigned short* __restrict__ packed) {
  const int idx = blockIdx.x * 256 + threadIdx.x;  // 0..65535
  const int j = idx & 7;
  const int l = (idx >> 3) & 63;
  const int nt = (idx >> 9) & 7;
  const int g = idx >> 12;
  const int k = (((g >> 1) & 3) << 5) + ((l >> 4) << 3) + j;
  const int n = (nt << 4) + (l & 15);
  const float w = ((g < 8) ? Wl : Wr)[k * 128 + n];
  const unsigned short h = f32_to_bf16_rn(w);
  packed[idx] = (g & 1) ? f32_to_bf16_rn(w - bf16_to_f32(h)) : h;
}

// ---------------- CSR build ----------------
__global__ void hist_k(const int* __restrict__ dst, int* __restrict__ deg) {
  int e = blockIdx.x * blockDim.x + threadIdx.x;
  if (e < N_EDGES) atomicAdd(&deg[dst[e]], 1);
}

__global__ __launch_bounds__(1024) void scan1_k(const int* __restrict__ deg,
                                                int* __restrict__ incl,
                                                int* __restrict__ bsum) {
  __shared__ int wsum[16];
  const int t = threadIdx.x, lane = t & 63, w = t >> 6;
  const int gi = blockIdx.x * 1024 + t;
  int v = (gi < N_NODES) ? deg[gi] : 0;
  int s = v;
#pragma unroll
  for (int off = 1; off < 64; off <<= 1) {
    int u = __shfl_up(s, off);
    if (lane >= off) s += u;
  }
  if (lane == 63) wsum[w] = s;
  __syncthreads();
  if (t < 16) {
    int ws = wsum[t];
#pragma unroll
    for (int off = 1; off < 16; off <<= 1) {
      int u = __shfl_up(ws, off);
      if (t >= off) ws += u;
    }
    wsum[t] = ws;
  }
  __syncthreads();
  const int val = s + (w ? wsum[w - 1] : 0);
  if (gi < N_NODES) incl[gi] = val;
  if (t == 1023) bsum[blockIdx.x] = val;
}

__global__ void scan2_k(const int* __restrict__ bsum, int* __restrict__ boffs,
                        int nb) {
  __shared__ int w0;
  const int t = threadIdx.x;  // 128 threads
  int v = (t < nb) ? bsum[t] : 0;
  int s = v;
#pragma unroll
  for (int off = 1; off < 64; off <<= 1) {
    int u = __shfl_up(s, off);
    if ((t & 63) >= off) s += u;
  }
  if (t == 63) w0 = s;
  __syncthreads();
  const int excl = s - v + ((t >> 6) ? w0 : 0);
  if (t < nb) boffs[t] = excl;
}

__global__ __launch_bounds__(1024) void scan3_k(const int* __restrict__ deg,
                                                const int* __restrict__ incl,
                                                const int* __restrict__ boffs,
                                                int* __restrict__ rowptr,
                                                int* __restrict__ head) {
  const int gi = blockIdx.x * 1024 + threadIdx.x;
  if (gi < N_NODES) {
    const int e = incl[gi] - deg[gi] + boffs[blockIdx.x];
    rowptr[gi] = e;
    head[gi] = e;
  }
  if (gi == 0) rowptr[N_NODES] = N_EDGES;
}

__global__ void fill_k(const int* __restrict__ src, const int* __restrict__ dst,
                       int* __restrict__ head, int* __restrict__ col) {
  int e = blockIdx.x * blockDim.x + threadIdx.x;
  if (e < N_EDGES) {
    int p = atomicAdd(&head[dst[e]], 1);
    col[p] = src[e];
  }
}

// ---------------- mean aggregation: gather one u32 plane ----------------
// PACKED=0: plane holds f32 bits (layer 0: x). PACKED=1: plane holds
// (hi<<16|lo) bf16 pairs (layer 1: h1). Output: packed mean plane.
// 8 nodes / 256-thread block; 32 lanes per node (uint4 = 4 dims per lane).
template <int PACKED>
__global__ __launch_bounds__(256) void agg_k(
    const unsigned int* __restrict__ plane, const int* __restrict__ rowptr,
    const int* __restrict__ col, unsigned int* __restrict__ meanp) {
  const int t = threadIdx.x;
  const int node = blockIdx.x * 8 + (t >> 5);
  const int q = t & 31;  // uint4 index within the 128-dim row
  const int beg = rowptr[node], end = rowptr[node + 1];
  const uint4* P = reinterpret_cast<const uint4*>(plane);
  float a0 = 0.f, a1 = 0.f, a2 = 0.f, a3 = 0.f;

  auto accum = [&](uint4 v) {
    if (PACKED) {
      a0 += __builtin_bit_cast(float, v.x & 0xFFFF0000u);
      a0 += __builtin_bit_cast(float, v.x << 16);
      a1 += __builtin_bit_cast(float, v.y & 0xFFFF0000u);
      a1 += __builtin_bit_cast(float, v.y << 16);
      a2 += __builtin_bit_cast(float, v.z & 0xFFFF0000u);
      a2 += __builtin_bit_cast(float, v.z << 16);
      a3 += __builtin_bit_cast(float, v.w & 0xFFFF0000u);
      a3 += __builtin_bit_cast(float, v.w << 16);
    } else {
      a0 += __builtin_bit_cast(float, v.x);
      a1 += __builtin_bit_cast(float, v.y);
      a2 += __builtin_bit_cast(float, v.z);
      a3 += __builtin_bit_cast(float, v.w);
    }
  };

  for (int i = beg; i < end; i += 4) {
    const int i1 = min(i + 1, end - 1);
    const int i2 = min(i + 2, end - 1);
    const int i3 = min(i + 3, end - 1);
    const int c0 = col[i], c1 = col[i1], c2 = col[i2], c3 = col[i3];
    const uint4 v0 = P[(size_t)c0 * 32 + q];
    const uint4 v1 = P[(size_t)c1 * 32 + q];
    const uint4 v2 = P[(size_t)c2 * 32 + q];
    const uint4 v3 = P[(size_t)c3 * 32 + q];
    accum(v0);
    if (i + 1 < end) accum(v1);
    if (i + 2 < end) accum(v2);
    if (i + 3 < end) accum(v3);
  }

  const int d = end - beg;
  const float inv = 1.0f / (float)(d > 1 ? d : 1);
  uint4 w;
  w.x = pack_hl(a0 * inv);
  w.y = pack_hl(a1 * inv);
  w.z = pack_hl(a2 * inv);
  w.w = pack_hl(a3 * inv);
  reinterpret_cast<uint4*>(meanp)[(size_t)node * 32 + q] = w;
}

// ---------------- fragment unpack helpers ----------------
__device__ __forceinline__ void unpack_pk(uint4 p0, uint4 p1, bf16x8& hi,
                                          bf16x8& lo) {
  const unsigned int u[8] = {p0.x, p0.y, p0.z, p0.w, p1.x, p1.y, p1.z, p1.w};
  uint4 hw, lw;
  unsigned int* hp = &hw.x;
  unsigned int* lp = &lw.x;
#pragma unroll
  for (int w = 0; w < 4; ++w) {
    hp[w] = __builtin_amdgcn_perm(u[2 * w + 1], u[2 * w], 0x07060302u);
    lp[w] = __builtin_amdgcn_perm(u[2 * w + 1], u[2 * w], 0x05040100u);
  }
  hi = __builtin_bit_cast(bf16x8, hw);
  lo = __builtin_bit_cast(bf16x8, lw);
}

__device__ __forceinline__ void split_f32(uint4 p0, uint4 p1, bf16x8& hi,
                                          bf16x8& lo) {
  const unsigned int u[8] = {p0.x, p0.y, p0.z, p0.w, p1.x, p1.y, p1.z, p1.w};
  unsigned int hb[8], l16[8];
#pragma unroll
  for (int e = 0; e < 8; ++e) {
    const unsigned int r1 = u[e] + 0x7FFFu + ((u[e] >> 16) & 1u);
    hb[e] = r1 & 0xFFFF0000u;
    const float fl = __builtin_bit_cast(float, u[e]) -
                     __builtin_bit_cast(float, hb[e]);
    const unsigned int u2 = __builtin_bit_cast(unsigned int, fl);
    l16[e] = (u2 + 0x7FFFu + ((u2 >> 16) & 1u)) >> 16;
  }
  uint4 hw, lw;
  unsigned int* hp = &hw.x;
  unsigned int* lp = &lw.x;
#pragma unroll
  for (int w = 0; w < 4; ++w) {
    hp[w] = (hb[2 * w] >> 16) | (hb[2 * w + 1] & 0xFFFF0000u);
    lp[w] = (l16[2 * w] & 0xFFFFu) | (l16[2 * w + 1] << 16);
  }
  hi = __builtin_bit_cast(bf16x8, hw);
  lo = __builtin_bit_cast(bf16x8, lw);
}

// ---------------- MFMA GEMM: out = relu(mean@Wl + b + h@Wr) ----------------
// Grid: 1564 blocks = 782 row-blocks x 2 N-halves (rb=bid>>1, nh=bid&1).
// Block: 256 thr / 4 waves; wave = 32 rows (2 m-tiles) x 64 cols (4 n-tiles).
// Phase 0 (ss 0-3): A-operand x Wl; phase 1 (ss 4-7): H-operand x Wr.
// Per phase: stage its 32 KB B-half into LDS ONCE, then run 4 super-steps
// barrier-free (ds_read + MFMA + A prefetched 2 ahead). 3 barriers total.
template <int HF32, int OUTF32>
__global__ __launch_bounds__(256, 3) void gemm_k(
    const unsigned int* __restrict__ Ap, const unsigned int* __restrict__ Hp,
    const unsigned short* __restrict__ Bp, const float* __restrict__ bias,
    unsigned int* __restrict__ Op, float* __restrict__ Of) {
  __shared__ unsigned short Bl[32 * 512];  // 32 KB: one phase, one N-half
  const int t = threadIdx.x;
  const int lane = t & 63;
  const int wid = t >> 6;
  const int rb = blockIdx.x >> 1, nh = blockIdx.x & 1;
  const int rbase = rb * 128 + wid * 32;
  const int lm = lane & 15, lk = lane >> 4;
  const size_t r0 = (size_t)min(rbase + lm, N_NODES - 1);
  const size_t r1 = (size_t)min(rbase + 16 + lm, N_NODES - 1);
  const uint4* PA = reinterpret_cast<const uint4*>(Ap);
  const uint4* PH = reinterpret_cast<const uint4*>(Hp);

  f32x4 acc[2][4] = {};

  // stage one phase: seg s=0..31 maps g = phase*8 + (s>>2), nt = nh*4 + (s&3)
  auto stageP = [&](int phase) {
#pragma unroll
    for (int i = 0; i < 8; ++i) {
      const int s = wid * 8 + i;
      const int g = phase * 8 + (s >> 2);
      const int nt = nh * 4 + (s & 3);
      stage16(Bp + ((size_t)(g * 8 + nt) * 64 + lane) * 8,
              &Bl[s * 512 + lane * 8]);
    }
  };

  uint4 abuf[8][4];
  auto loadA = [&](int ss) {
    const uint4* P = (ss < 4) ? PA : PH;
    const int kb = ((ss & 3) << 3) + lk * 2;
    abuf[ss][0] = P[r0 * 32 + kb];
    abuf[ss][1] = P[r0 * 32 + kb + 1];
    abuf[ss][2] = P[r1 * 32 + kb];
    abuf[ss][3] = P[r1 * 32 + kb + 1];
  };

  auto compute = [&](int ss) {
    bf16x8 fh0, fl0, fh1, fl1;
    if (HF32 && ss >= 4) {
      split_f32(abuf[ss][0], abuf[ss][1], fh0, fl0);
      split_f32(abuf[ss][2], abuf[ss][3], fh1, fl1);
    } else {
      unpack_pk(abuf[ss][0], abuf[ss][1], fh0, fl0);
      unpack_pk(abuf[ss][2], abuf[ss][3], fh1, fl1);
    }
    const int sb = (ss & 3) * 8;
#pragma unroll
    for (int nt = 0; nt < 4; ++nt) {
      const bf16x8 bh =
          *reinterpret_cast<const bf16x8*>(&Bl[((sb + nt) * 64 + lane) * 8]);
      acc[0][nt] = __builtin_amdgcn_mfma_f32_16x16x32_bf16(fh0, bh, acc[0][nt], 0, 0, 0);
      acc[1][nt] = __builtin_amdgcn_mfma_f32_16x16x32_bf16(fh1, bh, acc[1][nt], 0, 0, 0);
      const bf16x8 bl = *reinterpret_cast<const bf16x8*>(
          &Bl[((sb + 4 + nt) * 64 + lane) * 8]);
      acc[0][nt] = __builtin_amdgcn_mfma_f32_16x16x32_bf16(fl0, bl, acc[0][nt], 0, 0, 0);
      acc[1][nt] = __builtin_amdgcn_mfma_f32_16x16x32_bf16(fl1, bl, acc[1][nt], 0, 0, 0);
    }
  };

  stageP(0);
  loadA(0);
  loadA(1);
  __syncthreads();
#pragma unroll
  for (int ss = 0; ss < 4; ++ss) {
    loadA(ss + 2);  // prefetch 2 ahead (abuf[2..5])
    compute(ss);
  }
  __syncthreads();  // all waves done reading phase-0 LDS
  stageP(1);
  __syncthreads();
#pragma unroll
  for (int ss = 4; ss < 8; ++ss) {
    if (ss < 6) loadA(ss + 2);  // abuf[6..7]
    compute(ss);
  }

#pragma unroll
  for (int nt = 0; nt < 4; ++nt) {
    const int cidx = nh * 64 + nt * 16 + lm;
    const float bv = bias[cidx];
#pragma unroll
    for (int mt = 0; mt < 2; ++mt) {
#pragma unroll
      for (int i = 0; i < 4; ++i) {
        const int r = rbase + mt * 16 + lk * 4 + i;
        if (r < N_NODES) {
          float v = acc[mt][nt][i] + bv;
          v = fmaxf(v, 0.0f);
          if (OUTF32) {
            Of[(size_t)r * DIM + cidx] = v;
          } else {
            Op[(size_t)r * DIM + cidx] = pack_hl(v);
          }
        }
      }
    }
  }
}

// ---------------- launcher ----------------
extern "C" void kernel_launch(void* const* d_in, const int* in_sizes, int n_in,
                              void* d_out, int out_size, void* d_ws,
                              size_t ws_size, hipStream_t stream) {
  const float* x = (const float*)d_in[0];
  const int* ei = (const int*)d_in[1];
  const float* Wl0 = (const float*)d_in[2];
  const float* bl0 = (const float*)d_in[3];
  const float* Wr0 = (const float*)d_in[4];
  const float* Wl1 = (const float*)d_in[5];
  const float* bl1 = (const float*)d_in[6];
  const float* Wr1 = (const float*)d_in[7];
  float* out = (float*)d_out;
  const int* src = ei;
  const int* dst = ei + N_EDGES;

  char* p = (char*)d_ws;
  auto alloc = [&](size_t bytes) {
    char* q = p;
    p += (bytes + 255) & ~(size_t)255;
    return q;
  };
  int* deg = (int*)alloc((size_t)N_NODES * 4);
  int* rowptr = (int*)alloc((size_t)(N_NODES + 1) * 4);
  int* head = (int*)alloc((size_t)N_NODES * 4);  // doubles as incl-scan temp
  int* col = (int*)alloc((size_t)N_EDGES * 4);
  int* bsum = (int*)alloc(128 * 4);
  int* boffs = (int*)alloc(128 * 4);
  unsigned short* Bp0 = (unsigned short*)alloc(65536 * 2);
  unsigned short* Bp1 = (unsigned short*)alloc(65536 * 2);
  unsigned int* meanp = (unsigned int*)alloc((size_t)N_NODES * DIM * 4);
  unsigned int* h1p = (unsigned int*)alloc((size_t)N_NODES * DIM * 4);

  const int nScanB = (N_NODES + 1023) / 1024;  // 98

  hipMemsetAsync(deg, 0, (size_t)N_NODES * 4, stream);
  pack_w_k<<<256, 256, 0, stream>>>(Wl0, Wr0, Bp0);
  pack_w_k<<<256, 256, 0, stream>>>(Wl1, Wr1, Bp1);
  hist_k<<<(N_EDGES + 255) / 256, 256, 0, stream>>>(dst, deg);
  scan1_k<<<nScanB, 1024, 0, stream>>>(deg, head, bsum);
  scan2_k<<<1, 128, 0, stream>>>(bsum, boffs, nScanB);
  scan3_k<<<nScanB, 1024, 0, stream>>>(deg, head, boffs, rowptr, head);
  fill_k<<<(N_EDGES + 255) / 256, 256, 0, stream>>>(src, dst, head, col);

  const int gemmBlocks = ((N_NODES + 127) / 128) * 2;  // 1564

  // layer 0: gather x (f32), write packed mean; gemm0: A=mean, H=x(f32)->h1p
  agg_k<0><<<N_NODES / 8, 256, 0, stream>>>((const unsigned int*)x, rowptr,
                                            col, meanp);
  gemm_k<1, 0><<<gemmBlocks, 256, 0, stream>>>(meanp, (const unsigned int*)x,
                                               Bp0, bl0, h1p, nullptr);
  // layer 1: gather h1p (packed), write packed mean; gemm1 -> f32 out
  agg_k<1><<<N_NODES / 8, 256, 0, stream>>>(h1p, rowptr, col, meanp);
  gemm_k<0, 1><<<gemmBlocks, 256, 0, stream>>>(meanp, h1p, Bp1, bl1, nullptr,
                                               out);
}

// Round 6
// 242.742 us; speedup vs baseline: 1.1217x; 1.1217x over previous
//
#include <hip/hip_runtime.h>

#define N_NODES 100000
#define N_EDGES 600000
#define DIM 128

typedef __attribute__((ext_vector_type(8))) short bf16x8;
typedef __attribute__((ext_vector_type(4))) float f32x4;

typedef __attribute__((address_space(1))) const unsigned int g_u32;
typedef __attribute__((address_space(3))) unsigned int l_u32;
__device__ __forceinline__ void stage16(const void* g, void* l) {
  __builtin_amdgcn_global_load_lds((g_u32*)g, (l_u32*)l, 16, 0, 0);
}

__device__ __forceinline__ unsigned short f32_to_bf16_rn(float f) {
  unsigned int u = __builtin_bit_cast(unsigned int, f);
  unsigned int r = (u + 0x7FFFu + ((u >> 16) & 1u)) >> 16;
  return (unsigned short)r;
}
__device__ __forceinline__ float bf16_to_f32(unsigned short h) {
  return __builtin_bit_cast(float, (unsigned int)h << 16);
}

// pack one f32 into u32 = (hi_bf16 << 16) | lo_bf16, hi=rn(v), lo=rn(v-hi)
__device__ __forceinline__ unsigned int pack_hl(float v) {
  const unsigned int u = __builtin_bit_cast(unsigned int, v);
  const unsigned int r1 = u + 0x7FFFu + ((u >> 16) & 1u);
  const unsigned int hb = r1 & 0xFFFF0000u;  // bf(hi) bits
  const float fl = v - __builtin_bit_cast(float, hb);
  const unsigned int u2 = __builtin_bit_cast(unsigned int, fl);
  const unsigned int r2 = (u2 + 0x7FFFu + ((u2 >> 16) & 1u)) >> 16;
  return hb | (r2 & 0xFFFFu);
}

// ---------------- pack weights into MFMA fragment order ----------------
// g-tile sequence (4096 shorts each): [Wl_hi k0-31, Wl_lo k0-31, Wl_hi k32-63,
// Wl_lo k32-63, ... , Wr_hi k0-31, Wr_lo k0-31, ...]
// packed[((g*8+nt)*64+l)*8+j] = plane[(g>>1)&3 k-tile][(l>>4)*8+j][nt*16+(l&15)]
__global__ __launch_bounds__(256) void pack_w_k(const float* __restrict__ Wl,
                                                const float* __restrict__ Wr,
                                                unsigned short* __restrict__ packed) {
  const int idx = blockIdx.x * 256 + threadIdx.x;  // 0..65535
  const int j = idx & 7;
  const int l = (idx >> 3) & 63;
  const int nt = (idx >> 9) & 7;
  const int g = idx >> 12;
  const int k = (((g >> 1) & 3) << 5) + ((l >> 4) << 3) + j;
  const int n = (nt << 4) + (l & 15);
  const float w = ((g < 8) ? Wl : Wr)[k * 128 + n];
  const unsigned short h = f32_to_bf16_rn(w);
  packed[idx] = (g & 1) ? f32_to_bf16_rn(w - bf16_to_f32(h)) : h;
}

// ---------------- CSR build ----------------
__global__ void hist_k(const int* __restrict__ dst, int* __restrict__ deg) {
  int e = blockIdx.x * blockDim.x + threadIdx.x;
  if (e < N_EDGES) atomicAdd(&deg[dst[e]], 1);
}

__global__ __launch_bounds__(1024) void scan1_k(const int* __restrict__ deg,
                                                int* __restrict__ incl,
                                                int* __restrict__ bsum) {
  __shared__ int wsum[16];
  const int t = threadIdx.x, lane = t & 63, w = t >> 6;
  const int gi = blockIdx.x * 1024 + t;
  int v = (gi < N_NODES) ? deg[gi] : 0;
  int s = v;
#pragma unroll
  for (int off = 1; off < 64; off <<= 1) {
    int u = __shfl_up(s, off);
    if (lane >= off) s += u;
  }
  if (lane == 63) wsum[w] = s;
  __syncthreads();
  if (t < 16) {
    int ws = wsum[t];
#pragma unroll
    for (int off = 1; off < 16; off <<= 1) {
      int u = __shfl_up(ws, off);
      if (t >= off) ws += u;
    }
    wsum[t] = ws;
  }
  __syncthreads();
  const int val = s + (w ? wsum[w - 1] : 0);
  if (gi < N_NODES) incl[gi] = val;
  if (t == 1023) bsum[blockIdx.x] = val;
}

__global__ void scan2_k(const int* __restrict__ bsum, int* __restrict__ boffs,
                        int nb) {
  __shared__ int w0;
  const int t = threadIdx.x;  // 128 threads
  int v = (t < nb) ? bsum[t] : 0;
  int s = v;
#pragma unroll
  for (int off = 1; off < 64; off <<= 1) {
    int u = __shfl_up(s, off);
    if ((t & 63) >= off) s += u;
  }
  if (t == 63) w0 = s;
  __syncthreads();
  const int excl = s - v + ((t >> 6) ? w0 : 0);
  if (t < nb) boffs[t] = excl;
}

__global__ __launch_bounds__(1024) void scan3_k(const int* __restrict__ deg,
                                                const int* __restrict__ incl,
                                                const int* __restrict__ boffs,
                                                int* __restrict__ rowptr,
                                                int* __restrict__ head) {
  const int gi = blockIdx.x * 1024 + threadIdx.x;
  if (gi < N_NODES) {
    const int e = incl[gi] - deg[gi] + boffs[blockIdx.x];
    rowptr[gi] = e;
    head[gi] = e;
  }
  if (gi == 0) rowptr[N_NODES] = N_EDGES;
}

__global__ void fill_k(const int* __restrict__ src, const int* __restrict__ dst,
                       int* __restrict__ head, int* __restrict__ col) {
  int e = blockIdx.x * blockDim.x + threadIdx.x;
  if (e < N_EDGES) {
    int p = atomicAdd(&head[dst[e]], 1);
    col[p] = src[e];
  }
}

// ---------------- mean aggregation: gather one u32 plane ----------------
// PACKED=0: plane holds f32 bits (layer 0: x). PACKED=1: plane holds
// (hi<<16|lo) bf16 pairs (layer 1: h1). Output: packed mean plane.
// 8 nodes / 256-thread block; 32 lanes per node (uint4 = 4 dims per lane).
template <int PACKED>
__global__ __launch_bounds__(256) void agg_k(
    const unsigned int* __restrict__ plane, const int* __restrict__ rowptr,
    const int* __restrict__ col, unsigned int* __restrict__ meanp) {
  const int t = threadIdx.x;
  const int node = blockIdx.x * 8 + (t >> 5);
  const int q = t & 31;  // uint4 index within the 128-dim row
  const int beg = rowptr[node], end = rowptr[node + 1];
  const uint4* P = reinterpret_cast<const uint4*>(plane);
  float a0 = 0.f, a1 = 0.f, a2 = 0.f, a3 = 0.f;

  auto accum = [&](uint4 v) {
    if (PACKED) {
      a0 += __builtin_bit_cast(float, v.x & 0xFFFF0000u);
      a0 += __builtin_bit_cast(float, v.x << 16);
      a1 += __builtin_bit_cast(float, v.y & 0xFFFF0000u);
      a1 += __builtin_bit_cast(float, v.y << 16);
      a2 += __builtin_bit_cast(float, v.z & 0xFFFF0000u);
      a2 += __builtin_bit_cast(float, v.z << 16);
      a3 += __builtin_bit_cast(float, v.w & 0xFFFF0000u);
      a3 += __builtin_bit_cast(float, v.w << 16);
    } else {
      a0 += __builtin_bit_cast(float, v.x);
      a1 += __builtin_bit_cast(float, v.y);
      a2 += __builtin_bit_cast(float, v.z);
      a3 += __builtin_bit_cast(float, v.w);
    }
  };

  for (int i = beg; i < end; i += 4) {
    const int i1 = min(i + 1, end - 1);
    const int i2 = min(i + 2, end - 1);
    const int i3 = min(i + 3, end - 1);
    const int c0 = col[i], c1 = col[i1], c2 = col[i2], c3 = col[i3];
    const uint4 v0 = P[(size_t)c0 * 32 + q];
    const uint4 v1 = P[(size_t)c1 * 32 + q];
    const uint4 v2 = P[(size_t)c2 * 32 + q];
    const uint4 v3 = P[(size_t)c3 * 32 + q];
    accum(v0);
    if (i + 1 < end) accum(v1);
    if (i + 2 < end) accum(v2);
    if (i + 3 < end) accum(v3);
  }

  const int d = end - beg;
  const float inv = 1.0f / (float)(d > 1 ? d : 1);
  uint4 w;
  w.x = pack_hl(a0 * inv);
  w.y = pack_hl(a1 * inv);
  w.z = pack_hl(a2 * inv);
  w.w = pack_hl(a3 * inv);
  reinterpret_cast<uint4*>(meanp)[(size_t)node * 32 + q] = w;
}

// ---------------- fragment unpack helpers ----------------
__device__ __forceinline__ void unpack_pk(uint4 p0, uint4 p1, bf16x8& hi,
                                          bf16x8& lo) {
  const unsigned int u[8] = {p0.x, p0.y, p0.z, p0.w, p1.x, p1.y, p1.z, p1.w};
  uint4 hw, lw;
  unsigned int* hp = &hw.x;
  unsigned int* lp = &lw.x;
#pragma unroll
  for (int w = 0; w < 4; ++w) {
    hp[w] = __builtin_amdgcn_perm(u[2 * w + 1], u[2 * w], 0x07060302u);
    lp[w] = __builtin_amdgcn_perm(u[2 * w + 1], u[2 * w], 0x05040100u);
  }
  hi = __builtin_bit_cast(bf16x8, hw);
  lo = __builtin_bit_cast(bf16x8, lw);
}

__device__ __forceinline__ void split_f32(uint4 p0, uint4 p1, bf16x8& hi,
                                          bf16x8& lo) {
  const unsigned int u[8] = {p0.x, p0.y, p0.z, p0.w, p1.x, p1.y, p1.z, p1.w};
  unsigned int hb[8], l16[8];
#pragma unroll
  for (int e = 0; e < 8; ++e) {
    const unsigned int r1 = u[e] + 0x7FFFu + ((u[e] >> 16) & 1u);
    hb[e] = r1 & 0xFFFF0000u;
    const float fl = __builtin_bit_cast(float, u[e]) -
                     __builtin_bit_cast(float, hb[e]);
    const unsigned int u2 = __builtin_bit_cast(unsigned int, fl);
    l16[e] = (u2 + 0x7FFFu + ((u2 >> 16) & 1u)) >> 16;
  }
  uint4 hw, lw;
  unsigned int* hp = &hw.x;
  unsigned int* lp = &lw.x;
#pragma unroll
  for (int w = 0; w < 4; ++w) {
    hp[w] = (hb[2 * w] >> 16) | (hb[2 * w + 1] & 0xFFFF0000u);
    lp[w] = (l16[2 * w] & 0xFFFFu) | (l16[2 * w + 1] << 16);
  }
  hi = __builtin_bit_cast(bf16x8, hw);
  lo = __builtin_bit_cast(bf16x8, lw);
}

// ---------------- MFMA GEMM: out = relu(mean@Wl + b + h@Wr) ----------------
// Grid: 1563 blocks x 64 rows (row-split only -> no duplicated A/H fetch).
// Block: 256 thr / 4 waves; wave = 16 rows (1 m-tile) x N=128 (8 n-tiles).
// K loop: 16 g-tiles (hi/lo pairs). B: 8 KB/g-tile, double-buffered LDS via
// global_load_lds, ONE barrier per g-tile. A: one 32 B packed load pair per
// g-pair, register-prefetched one pair ahead (gives hi+lo fragments).
template <int HF32, int OUTF32>
__global__ __launch_bounds__(256, 4) void gemm_k(
    const unsigned int* __restrict__ Ap, const unsigned int* __restrict__ Hp,
    const unsigned short* __restrict__ Bp, const float* __restrict__ bias,
    unsigned int* __restrict__ Op, float* __restrict__ Of) {
  __shared__ unsigned short Bl[2][4096];  // 8 KB per buffer
  const int t = threadIdx.x;
  const int lane = t & 63;
  const int wid = t >> 6;
  const int rbase = blockIdx.x * 64 + wid * 16;
  const int lm = lane & 15, lk = lane >> 4;
  const size_t r0 = (size_t)min(rbase + lm, N_NODES - 1);
  const uint4* PA = reinterpret_cast<const uint4*>(Ap);
  const uint4* PH = reinterpret_cast<const uint4*>(Hp);

  f32x4 acc[8] = {};

  auto stageG = [&](int g, int nb) {
#pragma unroll
    for (int c = 0; c < 2; ++c) {
      const int e = (c * 256 + t) * 8;  // short index
      stage16(Bp + (size_t)g * 4096 + e, &Bl[nb][e]);
    }
  };
  auto loadPair = [&](int pp, uint4& q0, uint4& q1) {
    const uint4* P = (pp < 4) ? PA : PH;
    const int kb = ((pp & 3) << 3) + (lk << 1);
    q0 = P[r0 * 32 + kb];
    q1 = P[r0 * 32 + kb + 1];
  };

  uint4 c0, c1, n0, n1;
  stageG(0, 0);
  loadPair(0, c0, c1);
  __syncthreads();

  bf16x8 fh, fl;
#pragma unroll
  for (int g = 0; g < 16; ++g) {
    const int buf = g & 1;
    if (g < 15) stageG(g + 1, buf ^ 1);
    if ((g & 1) == 0) {
      const int pp = g >> 1;
      if (HF32 && pp >= 4) {
        split_f32(c0, c1, fh, fl);
      } else {
        unpack_pk(c0, c1, fh, fl);
      }
      if (pp < 7) loadPair(pp + 1, n0, n1);  // prefetch next A pair
    }
    const bf16x8 fa = (g & 1) ? fl : fh;
#pragma unroll
    for (int nt = 0; nt < 8; ++nt) {
      const bf16x8 b =
          *reinterpret_cast<const bf16x8*>(&Bl[buf][(nt * 64 + lane) * 8]);
      acc[nt] = __builtin_amdgcn_mfma_f32_16x16x32_bf16(fa, b, acc[nt], 0, 0, 0);
    }
    __syncthreads();
    if (g & 1) {
      c0 = n0;
      c1 = n1;
    }
  }

#pragma unroll
  for (int nt = 0; nt < 8; ++nt) {
    const int cidx = nt * 16 + lm;
    const float bv = bias[cidx];
#pragma unroll
    for (int i = 0; i < 4; ++i) {
      const int r = rbase + lk * 4 + i;
      if (r < N_NODES) {
        float v = acc[nt][i] + bv;
        v = fmaxf(v, 0.0f);
        if (OUTF32) {
          Of[(size_t)r * DIM + cidx] = v;
        } else {
          Op[(size_t)r * DIM + cidx] = pack_hl(v);
        }
      }
    }
  }
}

// ---------------- launcher ----------------
extern "C" void kernel_launch(void* const* d_in, const int* in_sizes, int n_in,
                              void* d_out, int out_size, void* d_ws,
                              size_t ws_size, hipStream_t stream) {
  const float* x = (const float*)d_in[0];
  const int* ei = (const int*)d_in[1];
  const float* Wl0 = (const float*)d_in[2];
  const float* bl0 = (const float*)d_in[3];
  const float* Wr0 = (const float*)d_in[4];
  const float* Wl1 = (const float*)d_in[5];
  const float* bl1 = (const float*)d_in[6];
  const float* Wr1 = (const float*)d_in[7];
  float* out = (float*)d_out;
  const int* src = ei;
  const int* dst = ei + N_EDGES;

  char* p = (char*)d_ws;
  auto alloc = [&](size_t bytes) {
    char* q = p;
    p += (bytes + 255) & ~(size_t)255;
    return q;
  };
  int* deg = (int*)alloc((size_t)N_NODES * 4);
  int* rowptr = (int*)alloc((size_t)(N_NODES + 1) * 4);
  int* head = (int*)alloc((size_t)N_NODES * 4);  // doubles as incl-scan temp
  int* col = (int*)alloc((size_t)N_EDGES * 4);
  int* bsum = (int*)alloc(128 * 4);
  int* boffs = (int*)alloc(128 * 4);
  unsigned short* Bp0 = (unsigned short*)alloc(65536 * 2);
  unsigned short* Bp1 = (unsigned short*)alloc(65536 * 2);
  unsigned int* meanp = (unsigned int*)alloc((size_t)N_NODES * DIM * 4);
  unsigned int* h1p = (unsigned int*)alloc((size_t)N_NODES * DIM * 4);

  const int nScanB = (N_NODES + 1023) / 1024;  // 98

  hipMemsetAsync(deg, 0, (size_t)N_NODES * 4, stream);
  pack_w_k<<<256, 256, 0, stream>>>(Wl0, Wr0, Bp0);
  pack_w_k<<<256, 256, 0, stream>>>(Wl1, Wr1, Bp1);
  hist_k<<<(N_EDGES + 255) / 256, 256, 0, stream>>>(dst, deg);
  scan1_k<<<nScanB, 1024, 0, stream>>>(deg, head, bsum);
  scan2_k<<<1, 128, 0, stream>>>(bsum, boffs, nScanB);
  scan3_k<<<nScanB, 1024, 0, stream>>>(deg, head, boffs, rowptr, head);
  fill_k<<<(N_EDGES + 255) / 256, 256, 0, stream>>>(src, dst, head, col);

  const int gemmBlocks = (N_NODES + 63) / 64;  // 1563

  // layer 0: gather x (f32), write packed mean; gemm0: A=mean, H=x(f32)->h1p
  agg_k<0><<<N_NODES / 8, 256, 0, stream>>>((const unsigned int*)x, rowptr,
                                            col, meanp);
  gemm_k<1, 0><<<gemmBlocks, 256, 0, stream>>>(meanp, (const unsigned int*)x,
                                               Bp0, bl0, h1p, nullptr);
  // layer 1: gather h1p (packed), write packed mean; gemm1 -> f32 out
  agg_k<1><<<N_NODES / 8, 256, 0, stream>>>(h1p, rowptr, col, meanp);
  gemm_k<0, 1><<<gemmBlocks, 256, 0, stream>>>(meanp, h1p, Bp1, bl1, nullptr,
                                               out);
}